// Round 8
// baseline (771.969 us; speedup 1.0000x reference)
//
#include <hip/hip_runtime.h>
#include <stdint.h>

#define NNODES 50000
#define NEDGES 800000
#define H 128
#define BN_EPS 1e-5f

typedef short short8 __attribute__((ext_vector_type(8)));
typedef short short4v __attribute__((ext_vector_type(4)));
typedef float f32x4 __attribute__((ext_vector_type(4)));

__device__ __forceinline__ float bf2f(unsigned short u) {
    unsigned int v = ((unsigned int)u) << 16;
    return __uint_as_float(v);
}
__device__ __forceinline__ unsigned short f2bf(float f) {
    unsigned int x = __float_as_uint(f);
    return (unsigned short)((x + 0x7FFFu + ((x >> 16) & 1u)) >> 16);
}
__device__ __forceinline__ short8 s8z() { short8 z = {0,0,0,0,0,0,0,0}; return z; }

// ================= common MFMA tile core (k_T / k_node1 / k_node2) =================
template<int KB>
__device__ __forceinline__ void gemm_tile(const short* __restrict__ sA, const int SK,
                                          const unsigned short* __restrict__ WT, const int RK,
                                          const int n0, f32x4 acc[4][4], const int lane) {
    const int mr = lane & 15, quad = lane >> 4;
    const short* W = (const short*)WT;
    #pragma unroll
    for (int kb = 0; kb < KB; ++kb) {
        short8 a[4];
        #pragma unroll
        for (int mt = 0; mt < 4; ++mt)
            a[mt] = *(const short8*)&sA[(mt*16 + mr)*SK + kb*32 + quad*8];
        #pragma unroll
        for (int nt = 0; nt < 4; ++nt) {
            short8 b = *(const short8*)&W[(size_t)(n0 + nt*16 + mr)*RK + kb*32 + quad*8];
            #pragma unroll
            for (int mt = 0; mt < 4; ++mt)
                acc[mt][nt] = __builtin_amdgcn_mfma_f32_16x16x32_bf16(a[mt], b, acc[mt][nt], 0, 0, 0);
        }
    }
}

// ---- fold We2@Wm -> W2m (f32), b2m = be2@Wm + bm ----
__global__ void k_fold(const float* __restrict__ We2, const float* __restrict__ be2,
                       const float* __restrict__ Wm, const float* __restrict__ bm,
                       float* __restrict__ W2m, float* __restrict__ b2m) {
    int j = threadIdx.x;
    int i = blockIdx.x;
    if (i < H) {
        float acc = 0.f;
        for (int k = 0; k < H; ++k) acc = fmaf(We2[i*H + k], Wm[k*H + j], acc);
        W2m[i*H + j] = acc;
    } else {
        float acc = bm[j];
        for (int k = 0; k < H; ++k) acc = fmaf(be2[k], Wm[k*H + j], acc);
        b2m[j] = acc;
    }
}

// ---- transposed bf16 weights + zero-init of cnt and BN-stat accumulators ----
__global__ void k_prep2(const float* __restrict__ We1, const float* __restrict__ Wn1,
                        const float* __restrict__ Wn2,
                        unsigned short* __restrict__ WabT, unsigned short* __restrict__ Wn1T,
                        unsigned short* __restrict__ Wn2T, unsigned short* __restrict__ WcT,
                        int* __restrict__ cnt, float* __restrict__ S1f) {
    int i = blockIdx.x*256 + threadIdx.x;
    if (i < 16384) {                        // WabT[256][64]
        int n = i >> 6, k = i & 63;
        WabT[n*64 + k] = f2bf(We1[(n < 128 ? k : 64 + k)*H + (n & 127)]);
    } else if (i < 40960) {                 // Wn1T[128][192]
        int j = i - 16384; int n = j / 192, k = j - n*192;
        Wn1T[n*192 + k] = f2bf(Wn1[k*H + n]);
    } else if (i < 57344) {                 // Wn2T[128][128]
        int j = i - 40960; int n = j >> 7, k = j & 127;
        Wn2T[n*H + k] = f2bf(Wn2[k*H + n]);
    } else if (i < 61440) {                 // WcT[128][32], k>=16 zero
        int j = i - 57344; int n = j >> 5, k = j & 31;
        WcT[n*32 + k] = (k < 16) ? f2bf(We1[(128 + k)*H + n]) : (unsigned short)0;
    } else if (i < 111440) {
        cnt[i - 61440] = 0;
    } else if (i < 112464) {
        S1f[i - 111440] = 0.f;
    }
}

// ---- CSR build ----
__global__ void k_count(const int* __restrict__ ei, int* __restrict__ cnt) {
    int e = blockIdx.x*256 + threadIdx.x;
    if (e < NEDGES) atomicAdd(&cnt[ei[e]], 1);
}

// multi-block scan: A = per-block sums, B = scan of block sums, C = final offsets
__global__ void k_scanA(const int* __restrict__ cnt, int* __restrict__ bsum) {
    __shared__ int ws[4];
    const int tid = threadIdx.x;
    int i = blockIdx.x*256 + tid;
    int v = (i < NNODES) ? cnt[i] : 0;
    #pragma unroll
    for (int off = 32; off > 0; off >>= 1) v += __shfl_down(v, off);
    if ((tid & 63) == 0) ws[tid >> 6] = v;
    __syncthreads();
    if (tid == 0) bsum[blockIdx.x] = ws[0] + ws[1] + ws[2] + ws[3];
}

__global__ void k_scanB(const int* __restrict__ bsum, int* __restrict__ bpre,
                        int* __restrict__ offsets) {
    __shared__ int ws[4];
    const int tid = threadIdx.x;
    const int lane = tid & 63, wid = tid >> 6;
    int v = (tid < 196) ? bsum[tid] : 0;
    int xv = v;
    #pragma unroll
    for (int off = 1; off < 64; off <<= 1) {
        int y = __shfl_up(xv, off);
        if (lane >= off) xv += y;
    }
    if (lane == 63) ws[wid] = xv;
    __syncthreads();
    int base = 0;
    for (int w = 0; w < 4; ++w) if (w < wid) base += ws[w];
    int incl = base + xv;
    if (tid < 196) bpre[tid] = incl - v;
    if (tid == 255) offsets[NNODES] = incl;
}

__global__ void k_scanC(const int* __restrict__ cnt, const int* __restrict__ bpre,
                        int* __restrict__ offsets, int* __restrict__ cursor) {
    __shared__ int ws[4];
    const int tid = threadIdx.x;
    const int lane = tid & 63, wid = tid >> 6;
    int i = blockIdx.x*256 + tid;
    int v = (i < NNODES) ? cnt[i] : 0;
    int xv = v;
    #pragma unroll
    for (int off = 1; off < 64; off <<= 1) {
        int y = __shfl_up(xv, off);
        if (lane >= off) xv += y;
    }
    if (lane == 63) ws[wid] = xv;
    __syncthreads();
    int base = bpre[blockIdx.x];
    for (int w = 0; w < 4; ++w) if (w < wid) base += ws[w];
    int excl = base + xv - v;
    if (i < NNODES) { offsets[i] = excl; cursor[i] = excl; }
}

__global__ void k_scatter(const int* __restrict__ ei, int* __restrict__ cursor,
                          int* __restrict__ elist) {
    int e = blockIdx.x*256 + threadIdx.x;
    if (e < NEDGES) {
        int p = atomicAdd(&cursor[ei[e]], 1);
        elist[p] = e;
    }
}

// ---- T = x @ [Wa | Wb]  (bf16 out, [50000][256]) ----
__launch_bounds__(256)
__global__ void k_T(const float* __restrict__ x, const unsigned short* __restrict__ WabT,
                    unsigned short* __restrict__ T) {
    __shared__ short sA[128*72];
    const int tid = threadIdx.x;
    const int n0b = blockIdx.x*128;
    {
        const int rowl = tid >> 1, half = (tid & 1)*32;
        const int node = n0b + rowl;
        const bool ok = node < NNODES;
        #pragma unroll
        for (int c = 0; c < 4; ++c) {
            int k0 = half + c*8;
            short8 o = s8z();
            if (ok) {
                float4 a = *(const float4*)&x[node*64 + k0];
                float4 b = *(const float4*)&x[node*64 + k0 + 4];
                o[0]=(short)f2bf(a.x); o[1]=(short)f2bf(a.y); o[2]=(short)f2bf(a.z); o[3]=(short)f2bf(a.w);
                o[4]=(short)f2bf(b.x); o[5]=(short)f2bf(b.y); o[6]=(short)f2bf(b.z); o[7]=(short)f2bf(b.w);
            }
            *(short8*)&sA[rowl*72 + k0] = o;
        }
    }
    __syncthreads();
    const int wave = tid >> 6, lane = tid & 63;
    const int m0 = (wave & 1)*64;
    const int n0 = blockIdx.y*128 + (wave >> 1)*64;
    f32x4 acc[4][4];
    f32x4 z = {0.f, 0.f, 0.f, 0.f};
    #pragma unroll
    for (int mt = 0; mt < 4; ++mt)
        #pragma unroll
        for (int nt = 0; nt < 4; ++nt) acc[mt][nt] = z;
    gemm_tile<2>(sA + m0*72, 72, WabT, 64, n0, acc, lane);
    const int mr = lane & 15, quad = lane >> 4;
    #pragma unroll
    for (int nt = 0; nt < 4; ++nt) {
        int j = n0 + nt*16 + mr;
        #pragma unroll
        for (int mt = 0; mt < 4; ++mt) {
            int nb = n0b + m0 + mt*16 + quad*4;
            #pragma unroll
            for (int r = 0; r < 4; ++r) {
                int node = nb + r;
                if (node < NNODES) T[(size_t)node*256 + j] = f2bf(acc[mt][nt][r]);
            }
        }
    }
}

// ---- h1[p] (sorted order, FRAGMENT layout) = T1[row]+T2[col]+ea@Wc+be1 ; BN stats ----
// 512 threads / 128 edges: same 36KB LDS (4 blocks/CU) but 8 waves/block ->
// 32 waves/CU (100% occupancy). Per-thread payload halves (4 T-loads) so the
// (512,8) 64-VGPR budget holds the full load batch. 4 threads/edge staging,
// each wave owns a 16-row band (all LDS access wave-local, barrier-free).
__launch_bounds__(512, 8)
__global__ void k_gather3(const unsigned short* __restrict__ T, const int* __restrict__ ei,
                          const int* __restrict__ elist, const float* __restrict__ ea,
                          const unsigned short* __restrict__ WcT, const float* __restrict__ be1,
                          unsigned short* __restrict__ hb,
                          float* __restrict__ gS, float* __restrict__ gSS) {
    __shared__ short sT[128*136];      // bf16(T1+T2), then finished h1 tile
    __shared__ float sS[H], sSS[H];
    const int tid = threadIdx.x;
    const int p0 = blockIdx.x*128;
    const int wave = tid >> 6, lane = tid & 63;
    const int mr = lane & 15, quad = lane >> 4;
    const int mbase = wave*16;
    const int lp = tid >> 2, q4 = tid & 3;
    const bool eaActive = (quad < 2);
    // ---- index loads ----
    const int e = elist[p0 + lp];
    int e0i = 0;
    if (eaActive) e0i = elist[p0 + mbase + mr];
    const int row = ei[e], col = ei[NEDGES + e];
    // ---- ea loads (wave covers its 16 edges; 2 lanes/edge) ----
    f32x4 u0, u1;
    if (eaActive) {
        u0 = __builtin_nontemporal_load((const f32x4*)&ea[(size_t)e0i*16 + quad*8]);
        u1 = __builtin_nontemporal_load((const f32x4*)&ea[(size_t)e0i*16 + quad*8 + 4]);
    }
    // ---- T gather: 4 threads/edge, each 64B of T1[row] and 64B of T2[col] ----
    const unsigned short* Tr = &T[(size_t)row*256 + q4*32];
    const unsigned short* Tc = &T[(size_t)col*256 + 128 + q4*32];
    short8 t1[4], t2[4];
    #pragma unroll
    for (int c = 0; c < 4; ++c) t1[c] = *(const short8*)&Tr[c*8];
    #pragma unroll
    for (int c = 0; c < 4; ++c) t2[c] = *(const short8*)&Tc[c*8];
    // ---- ea pack ----
    short8 a0 = s8z();
    if (eaActive) {
        a0[0]=(short)f2bf(u0[0]); a0[1]=(short)f2bf(u0[1]); a0[2]=(short)f2bf(u0[2]); a0[3]=(short)f2bf(u0[3]);
        a0[4]=(short)f2bf(u1[0]); a0[5]=(short)f2bf(u1[1]); a0[6]=(short)f2bf(u1[2]); a0[7]=(short)f2bf(u1[3]);
    }
    // ---- combine T1+T2 -> sT (own-wave rows: lp in [16w,16w+16)) ----
    #pragma unroll
    for (int c = 0; c < 4; ++c) {
        short8 o;
        #pragma unroll
        for (int i = 0; i < 8; ++i)
            o[i] = (short)f2bf(bf2f((unsigned short)t1[c][i]) + bf2f((unsigned short)t2[c][i]));
        *(short8*)&sT[lp*136 + q4*32 + c*8] = o;
    }
    // ---- ea @ Wc MFMA (one 16-row tile per wave) ----
    f32x4 acc[8];
    f32x4 z = {0.f, 0.f, 0.f, 0.f};
    #pragma unroll
    for (int nt = 0; nt < 8; ++nt) acc[nt] = z;
    #pragma unroll
    for (int nt = 0; nt < 8; ++nt) {
        short8 b = *(const short8*)&WcT[(nt*16 + mr)*32 + quad*8];
        acc[nt] = __builtin_amdgcn_mfma_f32_16x16x32_bf16(a0, b, acc[nt], 0, 0, 0);
    }
    // ---- epilogue (own-wave rows; barrier-free, within-wave lgkmcnt ordering) ----
    float sAcc[8], ssAcc[8];
    #pragma unroll
    for (int nt = 0; nt < 8; ++nt) {
        int j = nt*16 + mr;
        float bia = be1[j];
        float s = 0.f, ssum = 0.f;
        #pragma unroll
        for (int r = 0; r < 4; ++r) {
            int m = mbase + quad*4 + r;
            float v = acc[nt][r] + bf2f((unsigned short)sT[m*136 + j]) + bia;
            sT[m*136 + j] = (short)f2bf(v);
            s += v; ssum += v*v;
        }
        s += __shfl_xor(s, 16);
        ssum += __shfl_xor(ssum, 16);
        s += __shfl_xor(s, 32);
        ssum += __shfl_xor(ssum, 32);
        sAcc[nt] = s;
        ssAcc[nt] = ssum;
    }
    // ---- fragment-layout hb store (own-wave rows) ----
    #pragma unroll
    for (int c = 0; c < 4; ++c) {
        int k0 = q4*32 + c*8;
        short8 v = *(const short8*)&sT[lp*136 + k0];
        __builtin_nontemporal_store(v,
            (short8*)&hb[((size_t)(blockIdx.x*16 + q4*4 + c)*128 + lp)*8]);
    }
    // ---- BN-stat combine: the ONLY cross-wave dataflow ----
    if (tid < 128) { sS[tid] = 0.f; sSS[tid] = 0.f; }
    __syncthreads();
    if (quad == 0) {
        #pragma unroll
        for (int nt = 0; nt < 8; ++nt) {
            atomicAdd(&sS[nt*16 + mr], sAcc[nt]);
            atomicAdd(&sSS[nt*16 + mr], ssAcc[nt]);
        }
    }
    __syncthreads();
    if (tid < 128) { atomicAdd(&gS[tid], sS[tid]); atomicAdd(&gSS[tid], sSS[tid]); }
}

// ---- BN stats -> scale/shift ----
__global__ void k_stats(const float* __restrict__ S, const float* __restrict__ SS,
                        const float* __restrict__ g, const float* __restrict__ b,
                        float invCount, float* __restrict__ scale, float* __restrict__ shift) {
    int j = threadIdx.x;
    float mu = S[j]*invCount;
    float var = SS[j]*invCount - mu*mu;
    float sc = rsqrtf(var + BN_EPS)*g[j];
    scale[j] = sc;
    shift[j] = b[j] - mu*sc;
}

// ---- post-stats fold: W2mST[n][k] = bf16(sc[k]*W2m[k][n]); t = sh/sc; zero agg ----
__global__ void k_prep3(const float* __restrict__ W2m, const float* __restrict__ scale,
                        const float* __restrict__ shift, unsigned short* __restrict__ W2mST,
                        float* __restrict__ tvec, float* __restrict__ agg) {
    int i = blockIdx.x*256 + threadIdx.x;
    if (i < 16384) {
        int n = i >> 7, k = i & 127;
        W2mST[n*H + k] = f2bf(scale[k] * W2m[k*H + n]);
    } else if (i < 16512) {
        int k = i - 16384;
        tvec[k] = shift[k] / scale[k];
    } else if (i < 16512 + NNODES*H) {
        agg[i - 16512] = 0.f;
    }
}

// ---- fused: msg = relu( relu(h1+t) @ W2mS + b2m ) -> parallel segment-reduce -> agg ----
// 512 threads / 128 edges: 8 waves/block, each owning a 16-row band -> 32 waves/CU.
__launch_bounds__(512, 8)
__global__ void k_msgagg(const unsigned short* __restrict__ hb, const float* __restrict__ tvec,
                         const unsigned short* __restrict__ W2mST, const float* __restrict__ b2m,
                         const int* __restrict__ ei, const int* __restrict__ elist,
                         const int* __restrict__ offsets, float* __restrict__ agg) {
    __shared__ short sA[128*136];      // msg tile
    __shared__ int rows[128];
    __shared__ int segStart[130];
    __shared__ int wcnt[2];
    __shared__ int nsegS;
    const int tid = threadIdx.x;
    const int p0 = blockIdx.x*128;
    const int wave = tid >> 6, lane = tid & 63;
    const int mr = lane & 15, quad = lane >> 4;
    const int mbase = wave*16;
    // prefetch the wave's 4 A-fragments before the dependent ei[elist[...]] chain
    short8 raw[4];
    #pragma unroll
    for (int kb = 0; kb < 4; ++kb)
        raw[kb] = __builtin_nontemporal_load(
            (const short8*)&hb[((size_t)(blockIdx.x*16 + kb*4 + quad)*128
                                + mbase + mr)*8]);
    int pre = 0, st = 0;
    if (tid < 128) rows[tid] = ei[elist[p0 + tid]];
    __syncthreads();                   // B1
    if (tid < 128) {
        int r0 = rows[tid];
        st = (tid == 0) || (rows[tid - 1] != r0);
        unsigned long long m = __ballot(st);
        int lane2 = tid & 63;
        pre = __popcll(m & ((1ull << lane2) - 1ull));
        if (lane2 == 63) wcnt[tid >> 6] = pre + st;
    }
    __syncthreads();                   // B2
    if (tid < 128) {
        int base = (tid >= 64) ? wcnt[0] : 0;
        int sid = base + pre + st - 1;
        if (st) segStart[sid] = tid;
        if (tid == 127) {
            int ns = wcnt[0] + wcnt[1];
            nsegS = ns;
            segStart[ns] = 128;
        }
    }
    // barrier-free GEMM on prefetched A, B from L2-hot W2mST
    f32x4 acc[8];
    f32x4 z = {0.f, 0.f, 0.f, 0.f};
    #pragma unroll
    for (int nt = 0; nt < 8; ++nt) acc[nt] = z;
    #pragma unroll
    for (int kb = 0; kb < 4; ++kb) {
        float4 tq0 = *(const float4*)&tvec[kb*32 + quad*8];
        float4 tq1 = *(const float4*)&tvec[kb*32 + quad*8 + 4];
        short8 rw = raw[kb];
        short8 av;
        av[0] = (short)f2bf(fmaxf(bf2f((unsigned short)rw[0]) + tq0.x, 0.f));
        av[1] = (short)f2bf(fmaxf(bf2f((unsigned short)rw[1]) + tq0.y, 0.f));
        av[2] = (short)f2bf(fmaxf(bf2f((unsigned short)rw[2]) + tq0.z, 0.f));
        av[3] = (short)f2bf(fmaxf(bf2f((unsigned short)rw[3]) + tq0.w, 0.f));
        av[4] = (short)f2bf(fmaxf(bf2f((unsigned short)rw[4]) + tq1.x, 0.f));
        av[5] = (short)f2bf(fmaxf(bf2f((unsigned short)rw[5]) + tq1.y, 0.f));
        av[6] = (short)f2bf(fmaxf(bf2f((unsigned short)rw[6]) + tq1.z, 0.f));
        av[7] = (short)f2bf(fmaxf(bf2f((unsigned short)rw[7]) + tq1.w, 0.f));
        #pragma unroll
        for (int nt = 0; nt < 8; ++nt) {
            short8 b = *(const short8*)&W2mST[(nt*16 + mr)*H + kb*32 + quad*8];
            acc[nt] = __builtin_amdgcn_mfma_f32_16x16x32_bf16(av, b, acc[nt], 0, 0, 0);
        }
    }
    // msg -> LDS (own-wave rows)
    #pragma unroll
    for (int nt = 0; nt < 8; ++nt) {
        int j = nt*16 + mr;
        float bias = b2m[j];
        #pragma unroll
        for (int r = 0; r < 4; ++r) {
            int m = mbase + quad*4 + r;
            sA[m*136 + j] = (short)f2bf(fmaxf(acc[nt][r] + bias, 0.f));
        }
    }
    __syncthreads();                   // B3
    // vectorized segment reduce: item = (seg, 4-col group), 512 threads
    const int nseg = nsegS;
    for (int idx = tid; idx < (nseg << 5); idx += 512) {
        int s = idx >> 5, g = idx & 31;
        int j0 = g*4;
        int a0 = segStart[s], b0 = segStart[s + 1];
        float s0 = 0.f, s1 = 0.f, s2 = 0.f, s3 = 0.f;
        for (int i = a0; i < b0; ++i) {
            short4v v = *(const short4v*)&sA[i*136 + j0];
            s0 += bf2f((unsigned short)v[0]);
            s1 += bf2f((unsigned short)v[1]);
            s2 += bf2f((unsigned short)v[2]);
            s3 += bf2f((unsigned short)v[3]);
        }
        int r = rows[a0];
        bool interior = (a0 > 0) && (b0 < 128);
        bool full = interior || ((p0 + a0 == offsets[r]) && (p0 + b0 == offsets[r + 1]));
        float* dst = &agg[(size_t)r*H + j0];
        if (full) {
            f32x4 o = {s0, s1, s2, s3};
            *(f32x4*)dst = o;
        } else {
            atomicAdd(dst + 0, s0);
            atomicAdd(dst + 1, s1);
            atomicAdd(dst + 2, s2);
            atomicAdd(dst + 3, s3);
        }
    }
}

// ---- h2 = [x, agg] @ Wn1 + bn1 (f32 store) ; BN stats ----
__launch_bounds__(256)
__global__ void k_node1(const float* __restrict__ x, const float* __restrict__ agg,
                        const unsigned short* __restrict__ Wn1T, const float* __restrict__ bn1,
                        float* __restrict__ h2, float* __restrict__ gS, float* __restrict__ gSS) {
    __shared__ short sA[128*200];
    __shared__ float sS[H], sSS[H];
    const int tid = threadIdx.x;
    if (tid < H) { sS[tid] = 0.f; sSS[tid] = 0.f; }
    const int n0b = blockIdx.x*128;
    {
        const int rowl = tid >> 1, half = (tid & 1)*96;
        const int node = n0b + rowl;
        const bool ok = node < NNODES;
        #pragma unroll
        for (int c = 0; c < 12; ++c) {
            int k0 = half + c*8;
            short8 o = s8z();
            if (ok) {
                float4 a, b;
                if (k0 < 64) {
                    a = *(const float4*)&x[node*64 + k0];
                    b = *(const float4*)&x[node*64 + k0 + 4];
                } else {
                    a = *(const float4*)&agg[(size_t)node*H + (k0 - 64)];
                    b = *(const float4*)&agg[(size_t)node*H + (k0 - 64) + 4];
                }
                o[0]=(short)f2bf(a.x); o[1]=(short)f2bf(a.y); o[2]=(short)f2bf(a.z); o[3]=(short)f2bf(a.w);
                o[4]=(short)f2bf(b.x); o[5]=(short)f2bf(b.y); o[6]=(short)f2bf(b.z); o[7]=(short)f2bf(b.w);
            }
            *(short8*)&sA[rowl*200 + k0] = o;
        }
    }
    __syncthreads();
    const int wave = tid >> 6, lane = tid & 63;
    const int m0 = (wave & 1)*64, n0 = (wave >> 1)*64;
    f32x4 acc[4][4];
    f32x4 z = {0.f, 0.f, 0.f, 0.f};
    #pragma unroll
    for (int mt = 0; mt < 4; ++mt)
        #pragma unroll
        for (int nt = 0; nt < 4; ++nt) acc[mt][nt] = z;
    gemm_tile<6>(sA + m0*200, 200, Wn1T, 192, n0, acc, lane);
    const int mr = lane & 15, quad = lane >> 4;
    #pragma unroll
    for (int nt = 0; nt < 4; ++nt) {
        int j = n0 + nt*16 + mr;
        float bias = bn1[j];
        float s = 0.f, ssum = 0.f;
        #pragma unroll
        for (int mt = 0; mt < 4; ++mt) {
            int nb = n0b + m0 + mt*16 + quad*4;
            #pragma unroll
            for (int r = 0; r < 4; ++r) {
                int node = nb + r;
                if (node < NNODES) {
                    float v = acc[mt][nt][r] + bias;
                    h2[(size_t)node*H + j] = v;
                    s += v; ssum += v*v;
                }
            }
        }
        atomicAdd(&sS[j], s);
        atomicAdd(&sSS[j], ssum);
    }
    __syncthreads();
    if (tid < H) { atomicAdd(&gS[tid], sS[tid]); atomicAdd(&gSS[tid], sSS[tid]); }
}

// ---- out = relu(bn(h2)) @ Wn2 + bn2 (f32) ----
__launch_bounds__(256)
__global__ void k_node2(const float* __restrict__ h2, const float* __restrict__ scale,
                        const float* __restrict__ shift, const unsigned short* __restrict__ Wn2T,
                        const float* __restrict__ bn2, float* __restrict__ out) {
    __shared__ short sA[128*136];
    const int tid = threadIdx.x;
    const int n0b = blockIdx.x*128;
    {
        const int rowl = tid >> 1, half = (tid & 1)*64;
        const int node = n0b + rowl;
        const bool ok = node < NNODES;
        #pragma unroll
        for (int c = 0; c < 8; ++c) {
            int k0 = half + c*8;
            short8 o = s8z();
            if (ok) {
                float4 a = *(const float4*)&h2[(size_t)node*H + k0];
                float4 b = *(const float4*)&h2[(size_t)node*H + k0 + 4];
                float4 sc0 = *(const float4*)&scale[k0], sc1 = *(const float4*)&scale[k0 + 4];
                float4 sh0 = *(const float4*)&shift[k0], sh1 = *(const float4*)&shift[k0 + 4];
                o[0] = (short)f2bf(fmaxf(fmaf(a.x, sc0.x, sh0.x), 0.f));
                o[1] = (short)f2bf(fmaxf(fmaf(a.y, sc0.y, sh0.y), 0.f));
                o[2] = (short)f2bf(fmaxf(fmaf(a.z, sc0.z, sh0.z), 0.f));
                o[3] = (short)f2bf(fmaxf(fmaf(a.w, sc0.w, sh0.w), 0.f));
                o[4] = (short)f2bf(fmaxf(fmaf(b.x, sc1.x, sh1.x), 0.f));
                o[5] = (short)f2bf(fmaxf(fmaf(b.y, sc1.y, sh1.y), 0.f));
                o[6] = (short)f2bf(fmaxf(fmaf(b.z, sc1.z, sh1.z), 0.f));
                o[7] = (short)f2bf(fmaxf(fmaf(b.w, sc1.w, sh1.w), 0.f));
            }
            *(short8*)&sA[rowl*136 + k0] = o;
        }
    }
    __syncthreads();
    const int wave = tid >> 6, lane = tid & 63;
    const int m0 = (wave & 1)*64, n0 = (wave >> 1)*64;
    f32x4 acc[4][4];
    f32x4 z = {0.f, 0.f, 0.f, 0.f};
    #pragma unroll
    for (int mt = 0; mt < 4; ++mt)
        #pragma unroll
        for (int nt = 0; nt < 4; ++nt) acc[mt][nt] = z;
    gemm_tile<4>(sA + m0*136, 136, Wn2T, 128, n0, acc, lane);
    const int mr = lane & 15, quad = lane >> 4;
    #pragma unroll
    for (int nt = 0; nt < 4; ++nt) {
        int j = n0 + nt*16 + mr;
        float bias = bn2[j];
        #pragma unroll
        for (int mt = 0; mt < 4; ++mt) {
            int nb = n0b + m0 + mt*16 + quad*4;
            #pragma unroll
            for (int r = 0; r < 4; ++r) {
                int node = nb + r;
                if (node < NNODES) out[(size_t)node*H + j] = acc[mt][nt][r] + bias;
            }
        }
    }
}

extern "C" void kernel_launch(void* const* d_in, const int* in_sizes, int n_in,
                              void* d_out, int out_size, void* d_ws, size_t ws_size,
                              hipStream_t stream) {
    (void)in_sizes; (void)n_in; (void)out_size; (void)ws_size;
    const float* x   = (const float*)d_in[0];
    const int*   ei  = (const int*)d_in[1];
    const float* ea  = (const float*)d_in[2];
    const float* We1 = (const float*)d_in[3];
    const float* be1 = (const float*)d_in[4];
    const float* ge  = (const float*)d_in[5];
    const float* bbe = (const float*)d_in[6];
    const float* We2 = (const float*)d_in[7];
    const float* be2 = (const float*)d_in[8];
    const float* Wm  = (const float*)d_in[9];
    const float* bm  = (const float*)d_in[10];
    const float* Wn1 = (const float*)d_in[11];
    const float* bn1 = (const float*)d_in[12];
    const float* gn  = (const float*)d_in[13];
    const float* bbn = (const float*)d_in[14];
    const float* Wn2 = (const float*)d_in[15];
    const float* bn2 = (const float*)d_in[16];
    float* out = (float*)d_out;

    char* ws = (char*)d_ws;
    // [0, 204.8M)          h1 bf16 FRAGMENT layout (dead after k_msgagg; h2 f32 overlays)
    // [204.8M, 230.4M)     agg f32 [N][128]
    // [230.4M, 256M)       T bf16 [N][256] (dead after k_gather3)
    // [256M, ~260M)        CSR + scan temps + stats + folded weights
    unsigned short* hb   = (unsigned short*)(ws);
    float*          h2   = (float*)(ws);
    float*          agg  = (float*)(ws + 204800000);
    unsigned short* Tbuf = (unsigned short*)(ws + 230400000);
    int* cnt     = (int*)(ws + 256000000);
    int* offsets = (int*)(ws + 256200192);
    int* cursor  = (int*)(ws + 256400448);
    int* bsum    = (int*)(ws + 256600448);
    int* bpre    = (int*)(ws + 256601472);
    int* elist   = (int*)(ws + 256602496);
    float* S1     = (float*)(ws + 259802496);
    float* SS1    = S1 + 128;
    float* S2     = S1 + 256;
    float* SS2    = S1 + 384;
    float* scale1 = S1 + 512;
    float* shift1 = S1 + 640;
    float* scale2 = S1 + 768;
    float* shift2 = S1 + 896;
    float* W2m  = (float*)(ws + 259806592);
    float* b2m  = (float*)(ws + 259872128);
    float* tvec = (float*)(ws + 259872640);
    unsigned short* WabT  = (unsigned short*)(ws + 259873152);
    unsigned short* Wn1T  = (unsigned short*)(ws + 259905920);
    unsigned short* Wn2T  = (unsigned short*)(ws + 259955072);
    unsigned short* W2mST = (unsigned short*)(ws + 259987840);
    unsigned short* WcT   = (unsigned short*)(ws + 260020608);

    k_fold<<<H + 1, H, 0, stream>>>(We2, be2, Wm, bm, W2m, b2m);
    k_prep2<<<440, 256, 0, stream>>>(We1, Wn1, Wn2, WabT, Wn1T, Wn2T, WcT, cnt, S1);
    k_count<<<NEDGES/256, 256, 0, stream>>>(ei, cnt);
    k_scanA<<<196, 256, 0, stream>>>(cnt, bsum);
    k_scanB<<<1, 256, 0, stream>>>(bsum, bpre, offsets);
    k_scanC<<<196, 256, 0, stream>>>(cnt, bpre, offsets, cursor);
    k_scatter<<<NEDGES/256, 256, 0, stream>>>(ei, cursor, elist);
    k_T<<<dim3(391, 2), 256, 0, stream>>>(x, WabT, Tbuf);
    k_gather3<<<NEDGES/128, 512, 0, stream>>>(Tbuf, ei, elist, ea, WcT, be1, hb, S1, SS1);
    k_stats<<<1, H, 0, stream>>>(S1, SS1, ge, bbe, 1.0f/NEDGES, scale1, shift1);
    k_prep3<<<12565, 256, 0, stream>>>(W2m, scale1, shift1, W2mST, tvec, agg);
    k_msgagg<<<NEDGES/128, 512, 0, stream>>>(hb, tvec, W2mST, b2m, ei, elist, offsets, agg);
    k_node1<<<391, 256, 0, stream>>>(x, agg, Wn1T, bn1, h2, S2, SS2);
    k_stats<<<1, H, 0, stream>>>(S2, SS2, gn, bbn, 1.0f/NNODES, scale2, shift2);
    k_node2<<<391, 256, 0, stream>>>(h2, scale2, shift2, Wn2T, bn2, out);
}

// Round 9
// 642.062 us; speedup vs baseline: 1.2023x; 1.2023x over previous
//
#include <hip/hip_runtime.h>
#include <stdint.h>

#define NNODES 50000
#define NEDGES 800000
#define H 128
#define BN_EPS 1e-5f
#define NWG_EDGE (NEDGES/128)

typedef short short8 __attribute__((ext_vector_type(8)));
typedef short short4v __attribute__((ext_vector_type(4)));
typedef float f32x4 __attribute__((ext_vector_type(4)));

__device__ __forceinline__ float bf2f(unsigned short u) {
    unsigned int v = ((unsigned int)u) << 16;
    return __uint_as_float(v);
}
__device__ __forceinline__ unsigned short f2bf(float f) {
    unsigned int x = __float_as_uint(f);
    return (unsigned short)((x + 0x7FFFu + ((x >> 16) & 1u)) >> 16);
}
__device__ __forceinline__ short8 s8z() { short8 z = {0,0,0,0,0,0,0,0}; return z; }

// Bijective XCD-chunked swizzle (m204 form): HW dispatches consecutive blockIdx
// round-robin across 8 XCDs; this remap gives each XCD a CONTIGUOUS logical
// range, so row-sorted edge blocks that share T1 rows land in the same L2.
__device__ __forceinline__ int xcd_swz(int bid, int nwg) {
    int q = nwg >> 3, r = nwg & 7;
    int xcd = bid & 7, local = bid >> 3;
    return (xcd < r ? xcd*(q + 1) : r*(q + 1) + (xcd - r)*q) + local;
}

// ================= common MFMA tile core (k_T / k_node1 / k_node2) =================
template<int KB>
__device__ __forceinline__ void gemm_tile(const short* __restrict__ sA, const int SK,
                                          const unsigned short* __restrict__ WT, const int RK,
                                          const int n0, f32x4 acc[4][4], const int lane) {
    const int mr = lane & 15, quad = lane >> 4;
    const short* W = (const short*)WT;
    #pragma unroll
    for (int kb = 0; kb < KB; ++kb) {
        short8 a[4];
        #pragma unroll
        for (int mt = 0; mt < 4; ++mt)
            a[mt] = *(const short8*)&sA[(mt*16 + mr)*SK + kb*32 + quad*8];
        #pragma unroll
        for (int nt = 0; nt < 4; ++nt) {
            short8 b = *(const short8*)&W[(size_t)(n0 + nt*16 + mr)*RK + kb*32 + quad*8];
            #pragma unroll
            for (int mt = 0; mt < 4; ++mt)
                acc[mt][nt] = __builtin_amdgcn_mfma_f32_16x16x32_bf16(a[mt], b, acc[mt][nt], 0, 0, 0);
        }
    }
}

// ---- fold We2@Wm -> W2m (f32), b2m = be2@Wm + bm ----
__global__ void k_fold(const float* __restrict__ We2, const float* __restrict__ be2,
                       const float* __restrict__ Wm, const float* __restrict__ bm,
                       float* __restrict__ W2m, float* __restrict__ b2m) {
    int j = threadIdx.x;
    int i = blockIdx.x;
    if (i < H) {
        float acc = 0.f;
        for (int k = 0; k < H; ++k) acc = fmaf(We2[i*H + k], Wm[k*H + j], acc);
        W2m[i*H + j] = acc;
    } else {
        float acc = bm[j];
        for (int k = 0; k < H; ++k) acc = fmaf(be2[k], Wm[k*H + j], acc);
        b2m[j] = acc;
    }
}

// ---- transposed bf16 weights + zero-init of cnt and BN-stat accumulators ----
__global__ void k_prep2(const float* __restrict__ We1, const float* __restrict__ Wn1,
                        const float* __restrict__ Wn2,
                        unsigned short* __restrict__ WabT, unsigned short* __restrict__ Wn1T,
                        unsigned short* __restrict__ Wn2T, unsigned short* __restrict__ WcT,
                        int* __restrict__ cnt, float* __restrict__ S1f) {
    int i = blockIdx.x*256 + threadIdx.x;
    if (i < 16384) {                        // WabT[256][64]
        int n = i >> 6, k = i & 63;
        WabT[n*64 + k] = f2bf(We1[(n < 128 ? k : 64 + k)*H + (n & 127)]);
    } else if (i < 40960) {                 // Wn1T[128][192]
        int j = i - 16384; int n = j / 192, k = j - n*192;
        Wn1T[n*192 + k] = f2bf(Wn1[k*H + n]);
    } else if (i < 57344) {                 // Wn2T[128][128]
        int j = i - 40960; int n = j >> 7, k = j & 127;
        Wn2T[n*H + k] = f2bf(Wn2[k*H + n]);
    } else if (i < 61440) {                 // WcT[128][32], k>=16 zero
        int j = i - 57344; int n = j >> 5, k = j & 31;
        WcT[n*32 + k] = (k < 16) ? f2bf(We1[(128 + k)*H + n]) : (unsigned short)0;
    } else if (i < 111440) {
        cnt[i - 61440] = 0;
    } else if (i < 112464) {
        S1f[i - 111440] = 0.f;
    }
}

// ---- CSR build ----
__global__ void k_count(const int* __restrict__ ei, int* __restrict__ cnt) {
    int e = blockIdx.x*256 + threadIdx.x;
    if (e < NEDGES) atomicAdd(&cnt[ei[e]], 1);
}

// multi-block scan: A = per-block sums, B = scan of block sums, C = final offsets
__global__ void k_scanA(const int* __restrict__ cnt, int* __restrict__ bsum) {
    __shared__ int ws[4];
    const int tid = threadIdx.x;
    int i = blockIdx.x*256 + tid;
    int v = (i < NNODES) ? cnt[i] : 0;
    #pragma unroll
    for (int off = 32; off > 0; off >>= 1) v += __shfl_down(v, off);
    if ((tid & 63) == 0) ws[tid >> 6] = v;
    __syncthreads();
    if (tid == 0) bsum[blockIdx.x] = ws[0] + ws[1] + ws[2] + ws[3];
}

__global__ void k_scanB(const int* __restrict__ bsum, int* __restrict__ bpre,
                        int* __restrict__ offsets) {
    __shared__ int ws[4];
    const int tid = threadIdx.x;
    const int lane = tid & 63, wid = tid >> 6;
    int v = (tid < 196) ? bsum[tid] : 0;
    int xv = v;
    #pragma unroll
    for (int off = 1; off < 64; off <<= 1) {
        int y = __shfl_up(xv, off);
        if (lane >= off) xv += y;
    }
    if (lane == 63) ws[wid] = xv;
    __syncthreads();
    int base = 0;
    for (int w = 0; w < 4; ++w) if (w < wid) base += ws[w];
    int incl = base + xv;
    if (tid < 196) bpre[tid] = incl - v;
    if (tid == 255) offsets[NNODES] = incl;
}

__global__ void k_scanC(const int* __restrict__ cnt, const int* __restrict__ bpre,
                        int* __restrict__ offsets, int* __restrict__ cursor) {
    __shared__ int ws[4];
    const int tid = threadIdx.x;
    const int lane = tid & 63, wid = tid >> 6;
    int i = blockIdx.x*256 + tid;
    int v = (i < NNODES) ? cnt[i] : 0;
    int xv = v;
    #pragma unroll
    for (int off = 1; off < 64; off <<= 1) {
        int y = __shfl_up(xv, off);
        if (lane >= off) xv += y;
    }
    if (lane == 63) ws[wid] = xv;
    __syncthreads();
    int base = bpre[blockIdx.x];
    for (int w = 0; w < 4; ++w) if (w < wid) base += ws[w];
    int excl = base + xv - v;
    if (i < NNODES) { offsets[i] = excl; cursor[i] = excl; }
}

__global__ void k_scatter(const int* __restrict__ ei, int* __restrict__ cursor,
                          int* __restrict__ elist) {
    int e = blockIdx.x*256 + threadIdx.x;
    if (e < NEDGES) {
        int p = atomicAdd(&cursor[ei[e]], 1);
        elist[p] = e;
    }
}

// ---- T = x @ [Wa | Wb]  (bf16 out, [50000][256]) ----
__launch_bounds__(256)
__global__ void k_T(const float* __restrict__ x, const unsigned short* __restrict__ WabT,
                    unsigned short* __restrict__ T) {
    __shared__ short sA[128*72];
    const int tid = threadIdx.x;
    const int n0b = blockIdx.x*128;
    {
        const int rowl = tid >> 1, half = (tid & 1)*32;
        const int node = n0b + rowl;
        const bool ok = node < NNODES;
        #pragma unroll
        for (int c = 0; c < 4; ++c) {
            int k0 = half + c*8;
            short8 o = s8z();
            if (ok) {
                float4 a = *(const float4*)&x[node*64 + k0];
                float4 b = *(const float4*)&x[node*64 + k0 + 4];
                o[0]=(short)f2bf(a.x); o[1]=(short)f2bf(a.y); o[2]=(short)f2bf(a.z); o[3]=(short)f2bf(a.w);
                o[4]=(short)f2bf(b.x); o[5]=(short)f2bf(b.y); o[6]=(short)f2bf(b.z); o[7]=(short)f2bf(b.w);
            }
            *(short8*)&sA[rowl*72 + k0] = o;
        }
    }
    __syncthreads();
    const int wave = tid >> 6, lane = tid & 63;
    const int m0 = (wave & 1)*64;
    const int n0 = blockIdx.y*128 + (wave >> 1)*64;
    f32x4 acc[4][4];
    f32x4 z = {0.f, 0.f, 0.f, 0.f};
    #pragma unroll
    for (int mt = 0; mt < 4; ++mt)
        #pragma unroll
        for (int nt = 0; nt < 4; ++nt) acc[mt][nt] = z;
    gemm_tile<2>(sA + m0*72, 72, WabT, 64, n0, acc, lane);
    const int mr = lane & 15, quad = lane >> 4;
    #pragma unroll
    for (int nt = 0; nt < 4; ++nt) {
        int j = n0 + nt*16 + mr;
        #pragma unroll
        for (int mt = 0; mt < 4; ++mt) {
            int nb = n0b + m0 + mt*16 + quad*4;
            #pragma unroll
            for (int r = 0; r < 4; ++r) {
                int node = nb + r;
                if (node < NNODES) T[(size_t)node*256 + j] = f2bf(acc[mt][nt][r]);
            }
        }
    }
}

// ---- h1[p] (sorted order, FRAGMENT layout) = T1[row]+T2[col]+ea@Wc+be1 ; BN stats ----
// R2/R4 structure (best measured: 655 us) + XCD-chunked bid swizzle: row-sorted
// blocks sharing T1 rows land on the same XCD's L2.
__launch_bounds__(256, 4)
__global__ void k_gather3(const unsigned short* __restrict__ T, const int* __restrict__ ei,
                          const int* __restrict__ elist, const float* __restrict__ ea,
                          const unsigned short* __restrict__ WcT, const float* __restrict__ be1,
                          unsigned short* __restrict__ hb,
                          float* __restrict__ gS, float* __restrict__ gSS) {
    __shared__ short sT[128*136];      // bf16(T1+T2), then finished h1 tile
    __shared__ float sS[H], sSS[H];
    const int tid = threadIdx.x;
    const int bid = xcd_swz(blockIdx.x, NWG_EDGE);
    const int p0 = bid*128;
    const int wave = tid >> 6, lane = tid & 63;
    const int mr = lane & 15, quad = lane >> 4;
    const int mbase = wave*32;
    if (tid < 128) { sS[tid] = 0.f; sSS[tid] = 0.f; }
    // ---- index loads for both chains ----
    const int lp = tid >> 1, half = tid & 1;
    const int e = elist[p0 + lp];
    const bool eaActive = (quad < 2);
    int e0i = 0, e1i = 0;
    if (eaActive) {
        e0i = elist[p0 + mbase + mr];
        e1i = elist[p0 + mbase + 16 + mr];
    }
    const int row = ei[e], col = ei[NEDGES + e];
    // ---- ea loads ----
    f32x4 u0, u1, v0, v1;
    if (eaActive) {
        u0 = __builtin_nontemporal_load((const f32x4*)&ea[(size_t)e0i*16 + quad*8]);
        u1 = __builtin_nontemporal_load((const f32x4*)&ea[(size_t)e0i*16 + quad*8 + 4]);
        v0 = __builtin_nontemporal_load((const f32x4*)&ea[(size_t)e1i*16 + quad*8]);
        v1 = __builtin_nontemporal_load((const f32x4*)&ea[(size_t)e1i*16 + quad*8 + 4]);
    }
    // ---- T gather: all 16 loads issued ----
    const unsigned short* Tr = &T[(size_t)row*256 + half*64];
    const unsigned short* Tc = &T[(size_t)col*256 + 128 + half*64];
    short8 t1[8], t2[8];
    #pragma unroll
    for (int c = 0; c < 8; ++c) t1[c] = *(const short8*)&Tr[c*8];
    #pragma unroll
    for (int c = 0; c < 8; ++c) t2[c] = *(const short8*)&Tc[c*8];
    __builtin_amdgcn_sched_barrier(0);
    // ---- conversions (consume in issue order: ea first, then T) ----
    short8 a0 = s8z(), a1 = s8z();
    if (eaActive) {
        a0[0]=(short)f2bf(u0[0]); a0[1]=(short)f2bf(u0[1]); a0[2]=(short)f2bf(u0[2]); a0[3]=(short)f2bf(u0[3]);
        a0[4]=(short)f2bf(u1[0]); a0[5]=(short)f2bf(u1[1]); a0[6]=(short)f2bf(u1[2]); a0[7]=(short)f2bf(u1[3]);
        a1[0]=(short)f2bf(v0[0]); a1[1]=(short)f2bf(v0[1]); a1[2]=(short)f2bf(v0[2]); a1[3]=(short)f2bf(v0[3]);
        a1[4]=(short)f2bf(v1[0]); a1[5]=(short)f2bf(v1[1]); a1[6]=(short)f2bf(v1[2]); a1[7]=(short)f2bf(v1[3]);
    }
    #pragma unroll
    for (int c = 0; c < 8; ++c) {
        short8 o;
        #pragma unroll
        for (int i = 0; i < 8; ++i)
            o[i] = (short)f2bf(bf2f((unsigned short)t1[c][i]) + bf2f((unsigned short)t2[c][i]));
        *(short8*)&sT[lp*136 + half*64 + c*8] = o;
    }
    // ---- ea @ Wc MFMA ----
    f32x4 acc[2][8];
    f32x4 z = {0.f, 0.f, 0.f, 0.f};
    #pragma unroll
    for (int mt = 0; mt < 2; ++mt)
        #pragma unroll
        for (int nt = 0; nt < 8; ++nt) acc[mt][nt] = z;
    #pragma unroll
    for (int nt = 0; nt < 8; ++nt) {
        short8 b = *(const short8*)&WcT[(nt*16 + mr)*32 + quad*8];
        acc[0][nt] = __builtin_amdgcn_mfma_f32_16x16x32_bf16(a0, b, acc[0][nt], 0, 0, 0);
        acc[1][nt] = __builtin_amdgcn_mfma_f32_16x16x32_bf16(a1, b, acc[1][nt], 0, 0, 0);
    }
    __syncthreads();                   // B2: sT staging complete
    #pragma unroll
    for (int nt = 0; nt < 8; ++nt) {
        int j = nt*16 + mr;
        float bia = be1[j];
        float s = 0.f, ssum = 0.f;
        #pragma unroll
        for (int mt = 0; mt < 2; ++mt) {
            #pragma unroll
            for (int r = 0; r < 4; ++r) {
                int m = mbase + mt*16 + quad*4 + r;
                float v = acc[mt][nt][r] + bf2f((unsigned short)sT[m*136 + j]) + bia;
                sT[m*136 + j] = (short)f2bf(v);
                s += v; ssum += v*v;
            }
        }
        // 4 lanes (quads) share j: reduce in-register, 1 atomic instead of 4
        s += __shfl_xor(s, 16);
        ssum += __shfl_xor(ssum, 16);
        s += __shfl_xor(s, 32);
        ssum += __shfl_xor(ssum, 32);
        if (quad == 0) {
            atomicAdd(&sS[j], s);
            atomicAdd(&sSS[j], ssum);
        }
    }
    __syncthreads();                   // B3: h1 tile finished
    // fragment-layout coalesced store (nontemporal: write-once stream)
    #pragma unroll
    for (int c = 0; c < 8; ++c) {
        int k0 = half*64 + c*8;
        int kb = k0 >> 5, quadS = (k0 >> 3) & 3;
        short8 v = *(const short8*)&sT[lp*136 + k0];
        __builtin_nontemporal_store(v,
            (short8*)&hb[((size_t)(bid*16 + kb*4 + quadS)*128 + lp)*8]);
    }
    if (tid < 128) { atomicAdd(&gS[tid], sS[tid]); atomicAdd(&gSS[tid], sSS[tid]); }
}

// ---- BN stats -> scale/shift ----
__global__ void k_stats(const float* __restrict__ S, const float* __restrict__ SS,
                        const float* __restrict__ g, const float* __restrict__ b,
                        float invCount, float* __restrict__ scale, float* __restrict__ shift) {
    int j = threadIdx.x;
    float mu = S[j]*invCount;
    float var = SS[j]*invCount - mu*mu;
    float sc = rsqrtf(var + BN_EPS)*g[j];
    scale[j] = sc;
    shift[j] = b[j] - mu*sc;
}

// ---- post-stats fold: W2mST[n][k] = bf16(sc[k]*W2m[k][n]); t = sh/sc; zero agg ----
__global__ void k_prep3(const float* __restrict__ W2m, const float* __restrict__ scale,
                        const float* __restrict__ shift, unsigned short* __restrict__ W2mST,
                        float* __restrict__ tvec, float* __restrict__ agg) {
    int i = blockIdx.x*256 + threadIdx.x;
    if (i < 16384) {
        int n = i >> 7, k = i & 127;
        W2mST[n*H + k] = f2bf(scale[k] * W2m[k*H + n]);
    } else if (i < 16512) {
        int k = i - 16384;
        tvec[k] = shift[k] / scale[k];
    } else if (i < 16512 + NNODES*H) {
        agg[i - 16512] = 0.f;
    }
}

// ---- fused: msg = relu( relu(h1+t) @ W2mS + b2m ) -> parallel segment-reduce -> agg ----
__launch_bounds__(256)
__global__ void k_msgagg(const unsigned short* __restrict__ hb, const float* __restrict__ tvec,
                         const unsigned short* __restrict__ W2mST, const float* __restrict__ b2m,
                         const int* __restrict__ ei, const int* __restrict__ elist,
                         const int* __restrict__ offsets, float* __restrict__ agg) {
    __shared__ short sA[128*136];      // msg tile
    __shared__ int rows[128];
    __shared__ int segStart[130];
    __shared__ int wcnt[2];
    __shared__ int nsegS;
    const int tid = threadIdx.x;
    const int bid = xcd_swz(blockIdx.x, NWG_EDGE);
    const int p0 = bid*128;
    const int wave = tid >> 6, lane = tid & 63;
    const int mr = lane & 15, quad = lane >> 4;
    const int mbase = wave*32;
    // prefetch all 8 A-fragments before the dependent ei[elist[...]] chain
    short8 raw[4][2];
    #pragma unroll
    for (int kb = 0; kb < 4; ++kb)
        #pragma unroll
        for (int mt = 0; mt < 2; ++mt)
            raw[kb][mt] = __builtin_nontemporal_load(
                (const short8*)&hb[((size_t)(bid*16 + kb*4 + quad)*128
                                    + mbase + mt*16 + mr)*8]);
    int pre = 0, st = 0;
    if (tid < 128) rows[tid] = ei[elist[p0 + tid]];
    __syncthreads();                   // B1
    if (tid < 128) {
        int r0 = rows[tid];
        st = (tid == 0) || (rows[tid - 1] != r0);
        unsigned long long m = __ballot(st);
        int lane2 = tid & 63;
        pre = __popcll(m & ((1ull << lane2) - 1ull));
        if (lane2 == 63) wcnt[tid >> 6] = pre + st;
    }
    __syncthreads();                   // B2
    if (tid < 128) {
        int base = (tid >= 64) ? wcnt[0] : 0;
        int sid = base + pre + st - 1;
        if (st) segStart[sid] = tid;
        if (tid == 127) {
            int ns = wcnt[0] + wcnt[1];
            nsegS = ns;
            segStart[ns] = 128;
        }
    }
    // barrier-free GEMM on prefetched A, B from L2-hot W2mST
    f32x4 acc[2][8];
    f32x4 z = {0.f, 0.f, 0.f, 0.f};
    #pragma unroll
    for (int mt = 0; mt < 2; ++mt)
        #pragma unroll
        for (int nt = 0; nt < 8; ++nt) acc[mt][nt] = z;
    #pragma unroll
    for (int kb = 0; kb < 4; ++kb) {
        float4 tq0 = *(const float4*)&tvec[kb*32 + quad*8];
        float4 tq1 = *(const float4*)&tvec[kb*32 + quad*8 + 4];
        short8 a[2];
        #pragma unroll
        for (int mt = 0; mt < 2; ++mt) {
            short8 rw = raw[kb][mt];
            short8 av;
            av[0] = (short)f2bf(fmaxf(bf2f((unsigned short)rw[0]) + tq0.x, 0.f));
            av[1] = (short)f2bf(fmaxf(bf2f((unsigned short)rw[1]) + tq0.y, 0.f));
            av[2] = (short)f2bf(fmaxf(bf2f((unsigned short)rw[2]) + tq0.z, 0.f));
            av[3] = (short)f2bf(fmaxf(bf2f((unsigned short)rw[3]) + tq0.w, 0.f));
            av[4] = (short)f2bf(fmaxf(bf2f((unsigned short)rw[4]) + tq1.x, 0.f));
            av[5] = (short)f2bf(fmaxf(bf2f((unsigned short)rw[5]) + tq1.y, 0.f));
            av[6] = (short)f2bf(fmaxf(bf2f((unsigned short)rw[6]) + tq1.z, 0.f));
            av[7] = (short)f2bf(fmaxf(bf2f((unsigned short)rw[7]) + tq1.w, 0.f));
            a[mt] = av;
        }
        #pragma unroll
        for (int nt = 0; nt < 8; ++nt) {
            short8 b = *(const short8*)&W2mST[(nt*16 + mr)*H + kb*32 + quad*8];
            acc[0][nt] = __builtin_amdgcn_mfma_f32_16x16x32_bf16(a[0], b, acc[0][nt], 0, 0, 0);
            acc[1][nt] = __builtin_amdgcn_mfma_f32_16x16x32_bf16(a[1], b, acc[1][nt], 0, 0, 0);
        }
    }
    // msg -> LDS
    #pragma unroll
    for (int nt = 0; nt < 8; ++nt) {
        int j = nt*16 + mr;
        float bias = b2m[j];
        #pragma unroll
        for (int mt = 0; mt < 2; ++mt) {
            #pragma unroll
            for (int r = 0; r < 4; ++r) {
                int m = mbase + mt*16 + quad*4 + r;
                sA[m*136 + j] = (short)f2bf(fmaxf(acc[mt][nt][r] + bias, 0.f));
            }
        }
    }
    __syncthreads();                   // B3
    // vectorized segment reduce: item = (seg, 4-col group)
    const int nseg = nsegS;
    for (int idx = tid; idx < (nseg << 5); idx += 256) {
        int s = idx >> 5, g = idx & 31;
        int j0 = g*4;
        int a0 = segStart[s], b0 = segStart[s + 1];
        float s0 = 0.f, s1 = 0.f, s2 = 0.f, s3 = 0.f;
        for (int i = a0; i < b0; ++i) {
            short4v v = *(const short4v*)&sA[i*136 + j0];
            s0 += bf2f((unsigned short)v[0]);
            s1 += bf2f((unsigned short)v[1]);
            s2 += bf2f((unsigned short)v[2]);
            s3 += bf2f((unsigned short)v[3]);
        }
        int r = rows[a0];
        bool interior = (a0 > 0) && (b0 < 128);
        bool full = interior || ((p0 + a0 == offsets[r]) && (p0 + b0 == offsets[r + 1]));
        float* dst = &agg[(size_t)r*H + j0];
        if (full) {
            f32x4 o = {s0, s1, s2, s3};
            *(f32x4*)dst = o;
        } else {
            atomicAdd(dst + 0, s0);
            atomicAdd(dst + 1, s1);
            atomicAdd(dst + 2, s2);
            atomicAdd(dst + 3, s3);
        }
    }
}

// ---- h2 = [x, agg] @ Wn1 + bn1 (f32 store) ; BN stats ----
__launch_bounds__(256)
__global__ void k_node1(const float* __restrict__ x, const float* __restrict__ agg,
                        const unsigned short* __restrict__ Wn1T, const float* __restrict__ bn1,
                        float* __restrict__ h2, float* __restrict__ gS, float* __restrict__ gSS) {
    __shared__ short sA[128*200];
    __shared__ float sS[H], sSS[H];
    const int tid = threadIdx.x;
    if (tid < H) { sS[tid] = 0.f; sSS[tid] = 0.f; }
    const int n0b = blockIdx.x*128;
    {
        const int rowl = tid >> 1, half = (tid & 1)*96;
        const int node = n0b + rowl;
        const bool ok = node < NNODES;
        #pragma unroll
        for (int c = 0; c < 12; ++c) {
            int k0 = half + c*8;
            short8 o = s8z();
            if (ok) {
                float4 a, b;
                if (k0 < 64) {
                    a = *(const float4*)&x[node*64 + k0];
                    b = *(const float4*)&x[node*64 + k0 + 4];
                } else {
                    a = *(const float4*)&agg[(size_t)node*H + (k0 - 64)];
                    b = *(const float4*)&agg[(size_t)node*H + (k0 - 64) + 4];
                }
                o[0]=(short)f2bf(a.x); o[1]=(short)f2bf(a.y); o[2]=(short)f2bf(a.z); o[3]=(short)f2bf(a.w);
                o[4]=(short)f2bf(b.x); o[5]=(short)f2bf(b.y); o[6]=(short)f2bf(b.z); o[7]=(short)f2bf(b.w);
            }
            *(short8*)&sA[rowl*200 + k0] = o;
        }
    }
    __syncthreads();
    const int wave = tid >> 6, lane = tid & 63;
    const int m0 = (wave & 1)*64, n0 = (wave >> 1)*64;
    f32x4 acc[4][4];
    f32x4 z = {0.f, 0.f, 0.f, 0.f};
    #pragma unroll
    for (int mt = 0; mt < 4; ++mt)
        #pragma unroll
        for (int nt = 0; nt < 4; ++nt) acc[mt][nt] = z;
    gemm_tile<6>(sA + m0*200, 200, Wn1T, 192, n0, acc, lane);
    const int mr = lane & 15, quad = lane >> 4;
    #pragma unroll
    for (int nt = 0; nt < 4; ++nt) {
        int j = n0 + nt*16 + mr;
        float bias = bn1[j];
        float s = 0.f, ssum = 0.f;
        #pragma unroll
        for (int mt = 0; mt < 4; ++mt) {
            int nb = n0b + m0 + mt*16 + quad*4;
            #pragma unroll
            for (int r = 0; r < 4; ++r) {
                int node = nb + r;
                if (node < NNODES) {
                    float v = acc[mt][nt][r] + bias;
                    h2[(size_t)node*H + j] = v;
                    s += v; ssum += v*v;
                }
            }
        }
        atomicAdd(&sS[j], s);
        atomicAdd(&sSS[j], ssum);
    }
    __syncthreads();
    if (tid < H) { atomicAdd(&gS[tid], sS[tid]); atomicAdd(&gSS[tid], sSS[tid]); }
}

// ---- out = relu(bn(h2)) @ Wn2 + bn2 (f32) ----
__launch_bounds__(256)
__global__ void k_node2(const float* __restrict__ h2, const float* __restrict__ scale,
                        const float* __restrict__ shift, const unsigned short* __restrict__ Wn2T,
                        const float* __restrict__ bn2, float* __restrict__ out) {
    __shared__ short sA[128*136];
    const int tid = threadIdx.x;
    const int n0b = blockIdx.x*128;
    {
        const int rowl = tid >> 1, half = (tid & 1)*64;
        const int node = n0b + rowl;
        const bool ok = node < NNODES;
        #pragma unroll
        for (int c = 0; c < 8; ++c) {
            int k0 = half + c*8;
            short8 o = s8z();
            if (ok) {
                float4 a = *(const float4*)&h2[(size_t)node*H + k0];
                float4 b = *(const float4*)&h2[(size_t)node*H + k0 + 4];
                float4 sc0 = *(const float4*)&scale[k0], sc1 = *(const float4*)&scale[k0 + 4];
                float4 sh0 = *(const float4*)&shift[k0], sh1 = *(const float4*)&shift[k0 + 4];
                o[0] = (short)f2bf(fmaxf(fmaf(a.x, sc0.x, sh0.x), 0.f));
                o[1] = (short)f2bf(fmaxf(fmaf(a.y, sc0.y, sh0.y), 0.f));
                o[2] = (short)f2bf(fmaxf(fmaf(a.z, sc0.z, sh0.z), 0.f));
                o[3] = (short)f2bf(fmaxf(fmaf(a.w, sc0.w, sh0.w), 0.f));
                o[4] = (short)f2bf(fmaxf(fmaf(b.x, sc1.x, sh1.x), 0.f));
                o[5] = (short)f2bf(fmaxf(fmaf(b.y, sc1.y, sh1.y), 0.f));
                o[6] = (short)f2bf(fmaxf(fmaf(b.z, sc1.z, sh1.z), 0.f));
                o[7] = (short)f2bf(fmaxf(fmaf(b.w, sc1.w, sh1.w), 0.f));
            }
            *(short8*)&sA[rowl*136 + k0] = o;
        }
    }
    __syncthreads();
    const int wave = tid >> 6, lane = tid & 63;
    const int m0 = (wave & 1)*64, n0 = (wave >> 1)*64;
    f32x4 acc[4][4];
    f32x4 z = {0.f, 0.f, 0.f, 0.f};
    #pragma unroll
    for (int mt = 0; mt < 4; ++mt)
        #pragma unroll
        for (int nt = 0; nt < 4; ++nt) acc[mt][nt] = z;
    gemm_tile<4>(sA + m0*136, 136, Wn2T, 128, n0, acc, lane);
    const int mr = lane & 15, quad = lane >> 4;
    #pragma unroll
    for (int nt = 0; nt < 4; ++nt) {
        int j = n0 + nt*16 + mr;
        float bias = bn2[j];
        #pragma unroll
        for (int mt = 0; mt < 4; ++mt) {
            int nb = n0b + m0 + mt*16 + quad*4;
            #pragma unroll
            for (int r = 0; r < 4; ++r) {
                int node = nb + r;
                if (node < NNODES) out[(size_t)node*H + j] = acc[mt][nt][r] + bias;
            }
        }
    }
}

extern "C" void kernel_launch(void* const* d_in, const int* in_sizes, int n_in,
                              void* d_out, int out_size, void* d_ws, size_t ws_size,
                              hipStream_t stream) {
    (void)in_sizes; (void)n_in; (void)out_size; (void)ws_size;
    const float* x   = (const float*)d_in[0];
    const int*   ei  = (const int*)d_in[1];
    const float* ea  = (const float*)d_in[2];
    const float* We1 = (const float*)d_in[3];
    const float* be1 = (const float*)d_in[4];
    const float* ge  = (const float*)d_in[5];
    const float* bbe = (const float*)d_in[6];
    const float* We2 = (const float*)d_in[7];
    const float* be2 = (const float*)d_in[8];
    const float* Wm  = (const float*)d_in[9];
    const float* bm  = (const float*)d_in[10];
    const float* Wn1 = (const float*)d_in[11];
    const float* bn1 = (const float*)d_in[12];
    const float* gn  = (const float*)d_in[13];
    const float* bbn = (const float*)d_in[14];
    const float* Wn2 = (const float*)d_in[15];
    const float* bn2 = (const float*)d_in[16];
    float* out = (float*)d_out;

    char* ws = (char*)d_ws;
    // [0, 204.8M)          h1 bf16 FRAGMENT layout (dead after k_msgagg; h2 f32 overlays)
    // [204.8M, 230.4M)     agg f32 [N][128]
    // [230.4M, 256M)       T bf16 [N][256] (dead after k_gather3)
    // [256M, ~260M)        CSR + scan temps + stats + folded weights
    unsigned short* hb   = (unsigned short*)(ws);
    float*          h2   = (float*)(ws);
    float*          agg  = (float*)(ws + 204800000);
    unsigned short* Tbuf = (unsigned short*)(ws + 230400000);
    int* cnt     = (int*)(ws + 256000000);
    int* offsets = (int*)(ws + 256200192);
    int* cursor  = (int*)(ws + 256400448);
    int* bsum    = (int*)(ws + 256600448);
    int* bpre    = (int*)(ws + 256601472);
    int* elist   = (int*)(ws + 256602496);
    float* S1     = (float*)(ws + 259802496);
    float* SS1    = S1 + 128;
    float* S2     = S1 + 256;
    float* SS2    = S1 + 384;
    float* scale1 = S1 + 512;
    float* shift1 = S1 + 640;
    float* scale2 = S1 + 768;
    float* shift2 = S1 + 896;
    float* W2m  = (float*)(ws + 259806592);
    float* b2m  = (float*)(ws + 259872128);
    float* tvec = (float*)(ws + 259872640);
    unsigned short* WabT  = (unsigned short*)(ws + 259873152);
    unsigned short* Wn1T  = (unsigned short*)(ws + 259905920);
    unsigned short* Wn2T  = (unsigned short*)(ws + 259955072);
    unsigned short* W2mST = (unsigned short*)(ws + 259987840);
    unsigned short* WcT   = (unsigned short*)(ws + 260020608);

    k_fold<<<H + 1, H, 0, stream>>>(We2, be2, Wm, bm, W2m, b2m);
    k_prep2<<<440, 256, 0, stream>>>(We1, Wn1, Wn2, WabT, Wn1T, Wn2T, WcT, cnt, S1);
    k_count<<<NEDGES/256, 256, 0, stream>>>(ei, cnt);
    k_scanA<<<196, 256, 0, stream>>>(cnt, bsum);
    k_scanB<<<1, 256, 0, stream>>>(bsum, bpre, offsets);
    k_scanC<<<196, 256, 0, stream>>>(cnt, bpre, offsets, cursor);
    k_scatter<<<NEDGES/256, 256, 0, stream>>>(ei, cursor, elist);
    k_T<<<dim3(391, 2), 256, 0, stream>>>(x, WabT, Tbuf);
    k_gather3<<<NWG_EDGE, 256, 0, stream>>>(Tbuf, ei, elist, ea, WcT, be1, hb, S1, SS1);
    k_stats<<<1, H, 0, stream>>>(S1, SS1, ge, bbe, 1.0f/NEDGES, scale1, shift1);
    k_prep3<<<12565, 256, 0, stream>>>(W2m, scale1, shift1, W2mST, tvec, agg);
    k_msgagg<<<NWG_EDGE, 256, 0, stream>>>(hb, tvec, W2mST, b2m, ei, elist, offsets, agg);
    k_node1<<<391, 256, 0, stream>>>(x, agg, Wn1T, bn1, h2, S2, SS2);
    k_stats<<<1, H, 0, stream>>>(S2, SS2, gn, bbn, 1.0f/NNODES, scale2, shift2);
    k_node2<<<391, 256, 0, stream>>>(h2, scale2, shift2, Wn2T, bn2, out);
}